// Round 3
// baseline (1499.426 us; speedup 1.0000x reference)
//
#include <hip/hip_runtime.h>
#include <math.h>

#define NN 50000
#define NE 300000
#define IND 128
#define HIDD 64
#define HEADS 4
#define QKV 256      // HEADS*HIDD
#define OUTD 64

__device__ inline void atomicMaxF(float* addr, float val) {
    if (val >= 0.f) atomicMax((int*)addr, __float_as_int(val));
    else            atomicMin((unsigned int*)addr, __float_as_uint(val));
}

// ---------------- GEMM: Y[M][Nw] = X[M][128] @ W[128][Nw] + b ----------------
__global__ __launch_bounds__(256) void gemm_xw(const float* __restrict__ X,
                                               const float* __restrict__ W,
                                               const float* __restrict__ B,
                                               float* __restrict__ Y,
                                               int M, int Nw) {
    __shared__ float As[16][64];
    __shared__ float Bs[16][64];
    int tid = threadIdx.x;
    int tx = tid & 15, ty = tid >> 4;
    int row0 = blockIdx.x * 64;
    int col0 = blockIdx.y * 64;
    float acc[4][4] = {};
    for (int k0 = 0; k0 < 128; k0 += 16) {
#pragma unroll
        for (int i = 0; i < 4; i++) {
            int idx = tid + i * 256;
            int m = idx >> 4, kk = idx & 15;
            int r = row0 + m;
            As[kk][m] = (r < M) ? X[r * IND + k0 + kk] : 0.f;
        }
#pragma unroll
        for (int i = 0; i < 4; i++) {
            int idx = tid + i * 256;
            int kk = idx >> 6, n = idx & 63;
            Bs[kk][n] = W[(k0 + kk) * Nw + col0 + n];
        }
        __syncthreads();
#pragma unroll
        for (int kk = 0; kk < 16; kk++) {
            float a[4], b[4];
#pragma unroll
            for (int i = 0; i < 4; i++) a[i] = As[kk][ty * 4 + i];
#pragma unroll
            for (int j = 0; j < 4; j++) b[j] = Bs[kk][tx * 4 + j];
#pragma unroll
            for (int i = 0; i < 4; i++)
#pragma unroll
                for (int j = 0; j < 4; j++) acc[i][j] += a[i] * b[j];
        }
        __syncthreads();
    }
#pragma unroll
    for (int i = 0; i < 4; i++) {
        int r = row0 + ty * 4 + i;
        if (r < M) {
#pragma unroll
            for (int j = 0; j < 4; j++) {
                int c = col0 + tx * 4 + j;
                Y[r * Nw + c] = acc[i][j] + B[c];
            }
        }
    }
}

// ---------------- init m = -1e30, denom = 0 ----------------
__global__ void init_md(float* __restrict__ m, float* __restrict__ den) {
    int t = blockIdx.x * blockDim.x + threadIdx.x;
    if (t < NN * HEADS) { m[t] = -1e30f; den[t] = 0.f; }
}

__global__ void zero_f4(float4* __restrict__ p, int n4) {
    int t = blockIdx.x * blockDim.x + threadIdx.x;
    if (t < n4) p[t] = make_float4(0.f, 0.f, 0.f, 0.f);
}

// ---------------- edge pass A: alpha + segment max ----------------
__global__ __launch_bounds__(256) void edge_alpha(const int* __restrict__ ei,
                                                  const float* __restrict__ q,
                                                  const float* __restrict__ k,
                                                  float* __restrict__ alpha,
                                                  float* __restrict__ mbuf) {
    int wid = (blockIdx.x << 2) | (threadIdx.x >> 6);
    int lane = threadIdx.x & 63;
    if (wid >= NE) return;
    int src = ei[wid];
    int dst = ei[NE + wid];
    float4 qv = *(const float4*)(q + (size_t)dst * QKV + lane * 4);
    float4 kv = *(const float4*)(k + (size_t)src * QKV + lane * 4);
    float s = qv.x * kv.x + qv.y * kv.y + qv.z * kv.z + qv.w * kv.w;
    s += __shfl_xor(s, 1);
    s += __shfl_xor(s, 2);
    s += __shfl_xor(s, 4);
    s += __shfl_xor(s, 8);
    if ((lane & 15) == 0) {
        int h = lane >> 4;
        float a = s * 0.125f;   // / sqrt(64)
        alpha[wid * 4 + h] = a;
        atomicMaxF(mbuf + dst * 4 + h, a);
    }
}

// ---------------- edge pass B: ex + segment sum ----------------
__global__ __launch_bounds__(256) void edge_ex(const int* __restrict__ ei,
                                               const float* __restrict__ mbuf,
                                               float* __restrict__ alpha,
                                               float* __restrict__ den) {
    int t = blockIdx.x * blockDim.x + threadIdx.x;
    if (t >= NE * 4) return;
    int e = t >> 2, h = t & 3;
    int dst = ei[NE + e];
    float ex = expf(alpha[t] - mbuf[dst * 4 + h]);
    alpha[t] = ex;
    atomicAdd(den + dst * 4 + h, ex);
}

// ---------------- edge pass C: weighted aggregate ----------------
__global__ __launch_bounds__(256) void edge_agg(const int* __restrict__ ei,
                                                const float* __restrict__ alpha,
                                                const float* __restrict__ den,
                                                const float* __restrict__ v,
                                                float* __restrict__ agg) {
    int wid = (blockIdx.x << 2) | (threadIdx.x >> 6);
    int lane = threadIdx.x & 63;
    if (wid >= NE) return;
    int src = ei[wid];
    int dst = ei[NE + wid];
    int h = lane >> 4;
    float a = alpha[wid * 4 + h] / (den[dst * 4 + h] + 1e-16f);
    float4 vv = *(const float4*)(v + (size_t)src * QKV + lane * 4);
    float* base = agg + (size_t)dst * QKV + lane * 4;
    atomicAdd(base + 0, a * vv.x);
    atomicAdd(base + 1, a * vv.y);
    atomicAdd(base + 2, a * vv.z);
    atomicAdd(base + 3, a * vv.w);
}

// ---------------- spectral norm of Wmlp (64x64), 20 power iters ----------------
__global__ void spectral(const float* __restrict__ W, float* __restrict__ sigma) {
    __shared__ float ub[64], vb[64];
    int t = threadIdx.x;  // 64 threads, one wave
    ub[t] = 0.125f;       // ones(64)/||ones|| = 1/8
    __syncthreads();
    for (int it = 0; it < 20; it++) {
        float s = 0.f;
        for (int i = 0; i < 64; i++) s += W[i * 64 + t] * ub[i];
        float ss = s * s;
        for (int off = 1; off < 64; off <<= 1) ss += __shfl_xor(ss, off);
        float vn = s / (sqrtf(ss) + 1e-12f);
        __syncthreads();
        vb[t] = vn;
        __syncthreads();
        float s2 = 0.f;
        for (int j = 0; j < 64; j++) s2 += W[t * 64 + j] * vb[j];
        float ss2 = s2 * s2;
        for (int off = 1; off < 64; off <<= 1) ss2 += __shfl_xor(ss2, off);
        ub[t] = s2 / (sqrtf(ss2) + 1e-12f);
        __syncthreads();
    }
    float wv = 0.f;
    for (int j = 0; j < 64; j++) wv += W[t * 64 + j] * vb[j];
    float sg = ub[t] * wv;
    for (int off = 1; off < 64; off <<= 1) sg += __shfl_xor(sg, off);
    if (t == 0) *sigma = sg;
}

// ---------------- finalize: head-mean + skip, tanh, @ (Wmlp/sigma) ----------------
__global__ __launch_bounds__(256) void finalize(const float* __restrict__ agg,
                                                const float* __restrict__ skip,
                                                const float* __restrict__ Wmlp,
                                                const float* __restrict__ sigma,
                                                float* __restrict__ out) {
    __shared__ float Ws[64 * 64];
    __shared__ float hid[4][64];
    int tid = threadIdx.x;
    for (int i = tid; i < 64 * 64; i += 256) Ws[i] = Wmlp[i];
    float inv_sigma = 1.0f / (*sigma);
    __syncthreads();
    int wave = tid >> 6, lane = tid & 63;
    int n = blockIdx.x * 4 + wave;
    if (n < NN) {
        const float* a = agg + (size_t)n * QKV;
        float mval = 0.25f * (a[lane] + a[64 + lane] + a[128 + lane] + a[192 + lane])
                     + skip[(size_t)n * 64 + lane];
        hid[wave][lane] = tanhf(mval);
    }
    __syncthreads();
    if (n < NN) {
        float acc = 0.f;
        for (int d = 0; d < 64; d++) acc += hid[wave][d] * Ws[d * 64 + lane];
        out[(size_t)n * 64 + lane] = acc * inv_sigma;
    }
}

extern "C" void kernel_launch(void* const* d_in, const int* in_sizes, int n_in,
                              void* d_out, int out_size, void* d_ws, size_t ws_size,
                              hipStream_t stream) {
    const float* x     = (const float*)d_in[0];
    const int*   ei    = (const int*)d_in[1];
    const float* Wq    = (const float*)d_in[2];
    const float* bq    = (const float*)d_in[3];
    const float* Wk    = (const float*)d_in[4];
    const float* bk    = (const float*)d_in[5];
    const float* Wv    = (const float*)d_in[6];
    const float* bv    = (const float*)d_in[7];
    const float* Wskip = (const float*)d_in[8];
    const float* bskip = (const float*)d_in[9];
    const float* Wmlp  = (const float*)d_in[10];
    float* out = (float*)d_out;

    float* ws = (float*)d_ws;
    float* q    = ws;                       // NN*256
    float* kbuf = q    + (size_t)NN * QKV;  // NN*256
    float* vbuf = kbuf + (size_t)NN * QKV;  // NN*256
    float* skip = vbuf + (size_t)NN * QKV;  // NN*64
    float* alph = skip + (size_t)NN * OUTD; // NE*4
    float* mbuf = alph + (size_t)NE * 4;    // NN*4
    float* den  = mbuf + (size_t)NN * 4;    // NN*4
    float* sig  = den  + (size_t)NN * 4;    // 1
    float* agg  = q;                        // reuse q after edge_alpha

    // spectral sigma (independent, tiny)
    hipLaunchKernelGGL(spectral, dim3(1), dim3(64), 0, stream, Wmlp, sig);

    // GEMMs: q, k, v (N=256), skip (N=64)
    dim3 gq((NN + 63) / 64, QKV / 64);
    hipLaunchKernelGGL(gemm_xw, gq, dim3(256), 0, stream, x, Wq, bq, q, NN, QKV);
    hipLaunchKernelGGL(gemm_xw, gq, dim3(256), 0, stream, x, Wk, bk, kbuf, NN, QKV);
    hipLaunchKernelGGL(gemm_xw, gq, dim3(256), 0, stream, x, Wv, bv, vbuf, NN, QKV);
    dim3 gs((NN + 63) / 64, 1);
    hipLaunchKernelGGL(gemm_xw, gs, dim3(256), 0, stream, x, Wskip, bskip, skip, NN, OUTD);

    // init segment-max / denom
    hipLaunchKernelGGL(init_md, dim3((NN * 4 + 255) / 256), dim3(256), 0, stream, mbuf, den);

    // pass A: logits + max
    hipLaunchKernelGGL(edge_alpha, dim3(NE / 4), dim3(256), 0, stream, ei, q, kbuf, alph, mbuf);

    // zero agg (reuses q region, safe after edge_alpha in stream order)
    hipLaunchKernelGGL(zero_f4, dim3((NN * QKV / 4 + 255) / 256), dim3(256), 0, stream,
                       (float4*)agg, NN * QKV / 4);

    // pass B: exp + denom
    hipLaunchKernelGGL(edge_ex, dim3((NE * 4 + 255) / 256), dim3(256), 0, stream,
                       ei, mbuf, alph, den);

    // pass C: aggregate
    hipLaunchKernelGGL(edge_agg, dim3(NE / 4), dim3(256), 0, stream, ei, alph, den, vbuf, agg);

    // finalize
    hipLaunchKernelGGL(finalize, dim3(NN / 4), dim3(256), 0, stream, agg, skip, Wmlp, sig, out);
}

// Round 4
// 586.560 us; speedup vs baseline: 2.5563x; 2.5563x over previous
//
#include <hip/hip_runtime.h>
#include <math.h>

#define NN 50000
#define NE 300000
#define IND 128
#define HIDD 64
#define HEADS 4
#define QKV 256      // HEADS*HIDD
#define OUTD 64

// ---------------- GEMM: Y[M][Nw] = X[M][128] @ W[128][Nw] + b ----------------
__global__ __launch_bounds__(256) void gemm_xw(const float* __restrict__ X,
                                               const float* __restrict__ W,
                                               const float* __restrict__ B,
                                               float* __restrict__ Y,
                                               int M, int Nw) {
    __shared__ float As[16][64];
    __shared__ float Bs[16][64];
    int tid = threadIdx.x;
    int tx = tid & 15, ty = tid >> 4;
    int row0 = blockIdx.x * 64;
    int col0 = blockIdx.y * 64;
    float acc[4][4] = {};
    for (int k0 = 0; k0 < 128; k0 += 16) {
#pragma unroll
        for (int i = 0; i < 4; i++) {
            int idx = tid + i * 256;
            int m = idx >> 4, kk = idx & 15;
            int r = row0 + m;
            As[kk][m] = (r < M) ? X[r * IND + k0 + kk] : 0.f;
        }
#pragma unroll
        for (int i = 0; i < 4; i++) {
            int idx = tid + i * 256;
            int kk = idx >> 6, n = idx & 63;
            Bs[kk][n] = W[(k0 + kk) * Nw + col0 + n];
        }
        __syncthreads();
#pragma unroll
        for (int kk = 0; kk < 16; kk++) {
            float a[4], b[4];
#pragma unroll
            for (int i = 0; i < 4; i++) a[i] = As[kk][ty * 4 + i];
#pragma unroll
            for (int j = 0; j < 4; j++) b[j] = Bs[kk][tx * 4 + j];
#pragma unroll
            for (int i = 0; i < 4; i++)
#pragma unroll
                for (int j = 0; j < 4; j++) acc[i][j] += a[i] * b[j];
        }
        __syncthreads();
    }
#pragma unroll
    for (int i = 0; i < 4; i++) {
        int r = row0 + ty * 4 + i;
        if (r < M) {
#pragma unroll
            for (int j = 0; j < 4; j++) {
                int c = col0 + tx * 4 + j;
                Y[r * Nw + c] = acc[i][j] + B[c];
            }
        }
    }
}

// ---------------- CSR build ----------------
__global__ void zero_int(int* __restrict__ p, int n) {
    int t = blockIdx.x * blockDim.x + threadIdx.x;
    if (t < n) p[t] = 0;
}

__global__ void hist_dst(const int* __restrict__ ei, int* __restrict__ deg) {
    int t = blockIdx.x * blockDim.x + threadIdx.x;
    if (t < NE) atomicAdd(&deg[ei[NE + t]], 1);
}

// single-block exclusive scan over deg[0..NN) -> row_ptr[0..NN], plus cursor copy
__global__ __launch_bounds__(1024) void scan_deg(const int* __restrict__ deg,
                                                 int* __restrict__ row_ptr,
                                                 int* __restrict__ cursor) {
    __shared__ int s[1024];
    __shared__ int run_s;
    int tid = threadIdx.x;
    if (tid == 0) run_s = 0;
    __syncthreads();
    for (int base = 0; base < NN; base += 1024) {
        int idx = base + tid;
        int val = (idx < NN) ? deg[idx] : 0;
        s[tid] = val;
        __syncthreads();
        // Hillis-Steele inclusive scan
        for (int off = 1; off < 1024; off <<= 1) {
            int t2 = (tid >= off) ? s[tid - off] : 0;
            __syncthreads();
            s[tid] += t2;
            __syncthreads();
        }
        int running = run_s;
        int excl = running + s[tid] - val;
        if (idx < NN) { row_ptr[idx] = excl; cursor[idx] = excl; }
        __syncthreads();
        if (tid == 1023) run_s = running + s[1023];
        __syncthreads();
    }
    if (tid == 0) row_ptr[NN] = run_s;
}

__global__ void fill_csr(const int* __restrict__ ei, int* __restrict__ cursor,
                         int* __restrict__ col_src) {
    int t = blockIdx.x * blockDim.x + threadIdx.x;
    if (t < NE) {
        int src = ei[t];
        int dst = ei[NE + t];
        int pos = atomicAdd(&cursor[dst], 1);
        col_src[pos] = src;
    }
}

// ---------------- fused attention: one wave per dst node, online softmax ----------------
__global__ __launch_bounds__(256) void fused_attn(const int* __restrict__ row_ptr,
                                                  const int* __restrict__ col_src,
                                                  const float* __restrict__ q,
                                                  const float* __restrict__ k,
                                                  const float* __restrict__ v,
                                                  float* __restrict__ agg) {
    int wave = threadIdx.x >> 6;
    int lane = threadIdx.x & 63;
    int n = blockIdx.x * 4 + wave;
    if (n >= NN) return;

    float4 qv = *(const float4*)(q + (size_t)n * QKV + lane * 4);

    float m = -1e30f;       // running max (per head group; identical across 16 lanes)
    float d = 0.f;          // running denom
    float4 o = make_float4(0.f, 0.f, 0.f, 0.f);

    int jb = row_ptr[n], je = row_ptr[n + 1];
    for (int j = jb; j < je; j++) {
        int src = col_src[j];
        const float4 kv = *(const float4*)(k + (size_t)src * QKV + lane * 4);
        float s = qv.x * kv.x + qv.y * kv.y + qv.z * kv.z + qv.w * kv.w;
        // reduce over the 16 lanes of this head (64 dims / 4 per lane)
        s += __shfl_xor(s, 1);
        s += __shfl_xor(s, 2);
        s += __shfl_xor(s, 4);
        s += __shfl_xor(s, 8);
        s *= 0.125f;  // / sqrt(64)
        float mn = fmaxf(m, s);
        float scale = __expf(m - mn);   // m=-1e30 first iter -> 0
        float e = __expf(s - mn);
        d = d * scale + e;
        const float4 vv = *(const float4*)(v + (size_t)src * QKV + lane * 4);
        o.x = o.x * scale + e * vv.x;
        o.y = o.y * scale + e * vv.y;
        o.z = o.z * scale + e * vv.z;
        o.w = o.w * scale + e * vv.w;
        m = mn;
    }
    float inv = 1.0f / (d + 1e-16f);
    float4 r = make_float4(o.x * inv, o.y * inv, o.z * inv, o.w * inv);
    *(float4*)(agg + (size_t)n * QKV + lane * 4) = r;
}

// ---------------- spectral norm of Wmlp (64x64), 20 power iters ----------------
__global__ void spectral(const float* __restrict__ W, float* __restrict__ sigma) {
    __shared__ float ub[64], vb[64];
    int t = threadIdx.x;  // 64 threads, one wave
    ub[t] = 0.125f;       // ones(64)/||ones|| = 1/8
    __syncthreads();
    for (int it = 0; it < 20; it++) {
        float s = 0.f;
        for (int i = 0; i < 64; i++) s += W[i * 64 + t] * ub[i];
        float ss = s * s;
        for (int off = 1; off < 64; off <<= 1) ss += __shfl_xor(ss, off);
        float vn = s / (sqrtf(ss) + 1e-12f);
        __syncthreads();
        vb[t] = vn;
        __syncthreads();
        float s2 = 0.f;
        for (int j = 0; j < 64; j++) s2 += W[t * 64 + j] * vb[j];
        float ss2 = s2 * s2;
        for (int off = 1; off < 64; off <<= 1) ss2 += __shfl_xor(ss2, off);
        ub[t] = s2 / (sqrtf(ss2) + 1e-12f);
        __syncthreads();
    }
    float wv = 0.f;
    for (int j = 0; j < 64; j++) wv += W[t * 64 + j] * vb[j];
    float sg = ub[t] * wv;
    for (int off = 1; off < 64; off <<= 1) sg += __shfl_xor(sg, off);
    if (t == 0) *sigma = sg;
}

// ---------------- finalize: head-mean + skip, tanh, @ (Wmlp/sigma) ----------------
__global__ __launch_bounds__(256) void finalize(const float* __restrict__ agg,
                                                const float* __restrict__ skip,
                                                const float* __restrict__ Wmlp,
                                                const float* __restrict__ sigma,
                                                float* __restrict__ out) {
    __shared__ float Ws[64 * 64];
    __shared__ float hid[4][64];
    int tid = threadIdx.x;
    for (int i = tid; i < 64 * 64; i += 256) Ws[i] = Wmlp[i];
    float inv_sigma = 1.0f / (*sigma);
    __syncthreads();
    int wave = tid >> 6, lane = tid & 63;
    int n = blockIdx.x * 4 + wave;
    if (n < NN) {
        const float* a = agg + (size_t)n * QKV;
        float mval = 0.25f * (a[lane] + a[64 + lane] + a[128 + lane] + a[192 + lane])
                     + skip[(size_t)n * 64 + lane];
        hid[wave][lane] = tanhf(mval);
    }
    __syncthreads();
    if (n < NN) {
        float acc = 0.f;
        for (int d = 0; d < 64; d++) acc += hid[wave][d] * Ws[d * 64 + lane];
        out[(size_t)n * 64 + lane] = acc * inv_sigma;
    }
}

extern "C" void kernel_launch(void* const* d_in, const int* in_sizes, int n_in,
                              void* d_out, int out_size, void* d_ws, size_t ws_size,
                              hipStream_t stream) {
    const float* x     = (const float*)d_in[0];
    const int*   ei    = (const int*)d_in[1];
    const float* Wq    = (const float*)d_in[2];
    const float* bq    = (const float*)d_in[3];
    const float* Wk    = (const float*)d_in[4];
    const float* bk    = (const float*)d_in[5];
    const float* Wv    = (const float*)d_in[6];
    const float* bv    = (const float*)d_in[7];
    const float* Wskip = (const float*)d_in[8];
    const float* bskip = (const float*)d_in[9];
    const float* Wmlp  = (const float*)d_in[10];
    float* out = (float*)d_out;

    float* ws = (float*)d_ws;
    float* q    = ws;                       // NN*256
    float* kbuf = q    + (size_t)NN * QKV;  // NN*256
    float* vbuf = kbuf + (size_t)NN * QKV;  // NN*256
    float* agg  = vbuf + (size_t)NN * QKV;  // NN*256
    float* skip = agg  + (size_t)NN * QKV;  // NN*64
    float* sig  = skip + (size_t)NN * OUTD; // 1
    int* deg     = (int*)(sig + 1);         // NN
    int* row_ptr = deg + NN;                // NN+1
    int* cursor  = row_ptr + NN + 1;        // NN
    int* col_src = cursor + NN;             // NE

    // spectral sigma (independent, tiny)
    hipLaunchKernelGGL(spectral, dim3(1), dim3(64), 0, stream, Wmlp, sig);

    // CSR build (independent of GEMMs)
    hipLaunchKernelGGL(zero_int, dim3((NN + 255) / 256), dim3(256), 0, stream, deg, NN);
    hipLaunchKernelGGL(hist_dst, dim3((NE + 255) / 256), dim3(256), 0, stream, ei, deg);
    hipLaunchKernelGGL(scan_deg, dim3(1), dim3(1024), 0, stream, deg, row_ptr, cursor);
    hipLaunchKernelGGL(fill_csr, dim3((NE + 255) / 256), dim3(256), 0, stream, ei, cursor, col_src);

    // GEMMs: q, k, v (N=256), skip (N=64)
    dim3 gq((NN + 63) / 64, QKV / 64);
    hipLaunchKernelGGL(gemm_xw, gq, dim3(256), 0, stream, x, Wq, bq, q, NN, QKV);
    hipLaunchKernelGGL(gemm_xw, gq, dim3(256), 0, stream, x, Wk, bk, kbuf, NN, QKV);
    hipLaunchKernelGGL(gemm_xw, gq, dim3(256), 0, stream, x, Wv, bv, vbuf, NN, QKV);
    dim3 gs((NN + 63) / 64, 1);
    hipLaunchKernelGGL(gemm_xw, gs, dim3(256), 0, stream, x, Wskip, bskip, skip, NN, OUTD);

    // fused per-node attention (CSR gather, online softmax, no atomics)
    hipLaunchKernelGGL(fused_attn, dim3((NN + 3) / 4), dim3(256), 0, stream,
                       row_ptr, col_src, q, kbuf, vbuf, agg);

    // finalize
    hipLaunchKernelGGL(finalize, dim3((NN + 3) / 4), dim3(256), 0, stream,
                       agg, skip, Wmlp, sig, out);
}

// Round 6
// 344.395 us; speedup vs baseline: 4.3538x; 1.7032x over previous
//
#include <hip/hip_runtime.h>
#include <math.h>

#define NN 50000
#define NE 300000
#define IND 128
#define QKV 256      // HEADS*HID
#define OUTD 64
#define NTOT 832     // 256*3 + 64 packed output cols
#define SCAN_B 196   // ceil(NN/256)

typedef __attribute__((ext_vector_type(8))) short bf16x8;
typedef __attribute__((ext_vector_type(4))) float f32x4;

__device__ inline unsigned short f2bf(float f) {
    unsigned u = __float_as_uint(f);
    u = (u + 0x7FFFu + ((u >> 16) & 1u)) >> 16;   // RNE
    return (unsigned short)u;
}
__device__ inline float b2f(unsigned short h) {
    return __uint_as_float(((unsigned)h) << 16);
}

// ---------------- x -> bf16 ----------------
__global__ __launch_bounds__(256) void cvt_x(const float4* __restrict__ x4,
                                             ushort4* __restrict__ xh4) {
    int t = blockIdx.x * 256 + threadIdx.x;     // NN*128/4 threads exactly
    float4 v = x4[t];
    ushort4 o;
    o.x = f2bf(v.x); o.y = f2bf(v.y); o.z = f2bf(v.z); o.w = f2bf(v.w);
    xh4[t] = o;
}

// ---------------- pack W^T (bf16) + bias ----------------
__global__ __launch_bounds__(256) void pack_w(const float* __restrict__ Wq, const float* __restrict__ bq,
                                              const float* __restrict__ Wk, const float* __restrict__ bk,
                                              const float* __restrict__ Wv, const float* __restrict__ bv,
                                              const float* __restrict__ Wsk, const float* __restrict__ bsk,
                                              unsigned short* __restrict__ WT, float* __restrict__ bias) {
    int t = blockIdx.x * 256 + threadIdx.x;     // NTOT*128 threads
    if (t >= NTOT * 128) return;
    int col = t >> 7, kk = t & 127;
    const float* W; const float* B; int c; int ld;
    if (col < 256)      { W = Wq;  B = bq;  c = col;       ld = 256; }
    else if (col < 512) { W = Wk;  B = bk;  c = col - 256; ld = 256; }
    else if (col < 768) { W = Wv;  B = bv;  c = col - 512; ld = 256; }
    else                { W = Wsk; B = bsk; c = col - 768; ld = 64;  }
    WT[t] = f2bf(W[kk * ld + c]);               // WT[col][kk], t == col*128+kk
    if (kk == 0) bias[col] = B[c];
}

// ---------------- fused MFMA GEMM: [q|k|v|skip] = xh @ WT^T + bias ----------------
__global__ __launch_bounds__(256) void gemm_mfma(const unsigned short* __restrict__ xh,
                                                 const unsigned short* __restrict__ WT,
                                                 const float* __restrict__ bias,
                                                 float* __restrict__ q,
                                                 unsigned short* __restrict__ kh,
                                                 unsigned short* __restrict__ vh,
                                                 float* __restrict__ skip) {
    __shared__ short As[64][136];   // 64 rows x 128 k, +8 pad (bank spread)
    __shared__ short Bs[64][136];   // 64 cols x 128 k
    int tid = threadIdx.x;
    int wv = tid >> 6, lane = tid & 63;
    int row0 = blockIdx.x * 64, col0 = blockIdx.y * 64;

#pragma unroll
    for (int rr = 0; rr < 4; rr++) {            // stage A (16B per thread per pass)
        int idx = rr * 256 + tid;
        int r = idx >> 4, c8 = (idx & 15) * 8;
        int gr = row0 + r;
        int4 val = (gr < NN) ? *(const int4*)(xh + (size_t)gr * 128 + c8)
                             : make_int4(0, 0, 0, 0);
        *(int4*)(&As[r][c8]) = val;
    }
#pragma unroll
    for (int rr = 0; rr < 4; rr++) {            // stage B (WT rows = output cols)
        int idx = rr * 256 + tid;
        int r = idx >> 4, c8 = (idx & 15) * 8;
        *(int4*)(&Bs[r][c8]) = *(const int4*)(WT + (size_t)(col0 + r) * 128 + c8);
    }
    __syncthreads();

    int lr = lane & 15;
    int koff = (lane >> 4) * 8;
    int arow = wv * 16 + lr;
    f32x4 acc[4] = {};
#pragma unroll
    for (int k0 = 0; k0 < 128; k0 += 32) {
        bf16x8 a = *(bf16x8*)(&As[arow][k0 + koff]);
#pragma unroll
        for (int cf = 0; cf < 4; cf++) {
            bf16x8 b = *(bf16x8*)(&Bs[cf * 16 + lr][k0 + koff]);
            acc[cf] = __builtin_amdgcn_mfma_f32_16x16x32_bf16(a, b, acc[cf], 0, 0, 0);
        }
    }

    int rbase = wv * 16 + ((lane >> 4) << 2);
    if (col0 < 256) {                           // q fp32
#pragma unroll
        for (int cf = 0; cf < 4; cf++) {
            int c = col0 + cf * 16 + lr; float bb = bias[c];
#pragma unroll
            for (int r = 0; r < 4; r++) {
                int gr = row0 + rbase + r;
                if (gr < NN) q[(size_t)gr * QKV + c] = acc[cf][r] + bb;
            }
        }
    } else if (col0 < 512) {                    // k bf16
#pragma unroll
        for (int cf = 0; cf < 4; cf++) {
            int c = col0 + cf * 16 + lr; float bb = bias[c];
#pragma unroll
            for (int r = 0; r < 4; r++) {
                int gr = row0 + rbase + r;
                if (gr < NN) kh[(size_t)gr * QKV + (c - 256)] = f2bf(acc[cf][r] + bb);
            }
        }
    } else if (col0 < 768) {                    // v bf16
#pragma unroll
        for (int cf = 0; cf < 4; cf++) {
            int c = col0 + cf * 16 + lr; float bb = bias[c];
#pragma unroll
            for (int r = 0; r < 4; r++) {
                int gr = row0 + rbase + r;
                if (gr < NN) vh[(size_t)gr * QKV + (c - 512)] = f2bf(acc[cf][r] + bb);
            }
        }
    } else {                                    // skip fp32
#pragma unroll
        for (int cf = 0; cf < 4; cf++) {
            int c = col0 + cf * 16 + lr; float bb = bias[c];
#pragma unroll
            for (int r = 0; r < 4; r++) {
                int gr = row0 + rbase + r;
                if (gr < NN) skip[(size_t)gr * OUTD + (c - 768)] = acc[cf][r] + bb;
            }
        }
    }
}

// ---------------- CSR build ----------------
__global__ void zero_int(int* __restrict__ p, int n) {
    int t = blockIdx.x * blockDim.x + threadIdx.x;
    if (t < n) p[t] = 0;
}
__global__ void hist_dst(const int* __restrict__ ei, int* __restrict__ deg) {
    int t = blockIdx.x * blockDim.x + threadIdx.x;
    if (t < NE) atomicAdd(&deg[ei[NE + t]], 1);
}
__global__ __launch_bounds__(256) void scan1(const int* __restrict__ deg,
                                             int* __restrict__ incl, int* __restrict__ bsum) {
    __shared__ int s[256];
    int tid = threadIdx.x, i = blockIdx.x * 256 + tid;
    int v = (i < NN) ? deg[i] : 0;
    s[tid] = v; __syncthreads();
    for (int off = 1; off < 256; off <<= 1) {
        int t2 = (tid >= off) ? s[tid - off] : 0;
        __syncthreads(); s[tid] += t2; __syncthreads();
    }
    if (i < NN) incl[i] = s[tid];
    if (tid == 255) bsum[blockIdx.x] = s[255];
}
__global__ __launch_bounds__(256) void scan2(int* __restrict__ bsum, int* __restrict__ row_ptr) {
    __shared__ int s[256];
    int tid = threadIdx.x;
    int v = (tid < SCAN_B) ? bsum[tid] : 0;
    s[tid] = v; __syncthreads();
    for (int off = 1; off < 256; off <<= 1) {
        int t2 = (tid >= off) ? s[tid - off] : 0;
        __syncthreads(); s[tid] += t2; __syncthreads();
    }
    if (tid < SCAN_B) bsum[tid] = s[tid] - v;   // exclusive block offsets
    if (tid == 255) row_ptr[NN] = s[255];       // total = NE
}
__global__ __launch_bounds__(256) void scan3(const int* __restrict__ deg, const int* __restrict__ incl,
                                             const int* __restrict__ bsum,
                                             int* __restrict__ row_ptr, int* __restrict__ cursor) {
    int i = blockIdx.x * 256 + threadIdx.x;
    if (i < NN) {
        int e = incl[i] - deg[i] + bsum[blockIdx.x];
        row_ptr[i] = e; cursor[i] = e;
    }
}
__global__ void fill_csr(const int* __restrict__ ei, int* __restrict__ cursor,
                         int* __restrict__ col_src) {
    int t = blockIdx.x * blockDim.x + threadIdx.x;
    if (t < NE) {
        int pos = atomicAdd(&cursor[ei[NE + t]], 1);
        col_src[pos] = ei[t];
    }
}

// ---------------- fused attention: one wave per dst node, online softmax ----------------
__global__ __launch_bounds__(256) void fused_attn(const int* __restrict__ row_ptr,
                                                  const int* __restrict__ col_src,
                                                  const float* __restrict__ q,
                                                  const unsigned short* __restrict__ kh,
                                                  const unsigned short* __restrict__ vh,
                                                  float* __restrict__ agg) {
    int wv = threadIdx.x >> 6;
    int lane = threadIdx.x & 63;
    int n = blockIdx.x * 4 + wv;
    if (n >= NN) return;

    float4 qv = *(const float4*)(q + (size_t)n * QKV + lane * 4);
    float m = -1e30f, d = 0.f;
    float4 o = make_float4(0.f, 0.f, 0.f, 0.f);

    int jb = row_ptr[n], je = row_ptr[n + 1];
    for (int j = jb; j < je; j++) {
        int src = col_src[j];
        ushort4 kq = *(const ushort4*)(kh + (size_t)src * QKV + lane * 4);
        float s = qv.x * b2f(kq.x) + qv.y * b2f(kq.y) + qv.z * b2f(kq.z) + qv.w * b2f(kq.w);
        s += __shfl_xor(s, 1);
        s += __shfl_xor(s, 2);
        s += __shfl_xor(s, 4);
        s += __shfl_xor(s, 8);
        s *= 0.125f;                            // / sqrt(64)
        float mn = fmaxf(m, s);
        float scale = __expf(m - mn);
        float e = __expf(s - mn);
        d = d * scale + e;
        ushort4 vq = *(const ushort4*)(vh + (size_t)src * QKV + lane * 4);
        o.x = o.x * scale + e * b2f(vq.x);
        o.y = o.y * scale + e * b2f(vq.y);
        o.z = o.z * scale + e * b2f(vq.z);
        o.w = o.w * scale + e * b2f(vq.w);
        m = mn;
    }
    float inv = 1.0f / (d + 1e-16f);
    *(float4*)(agg + (size_t)n * QKV + lane * 4) =
        make_float4(o.x * inv, o.y * inv, o.z * inv, o.w * inv);
}

// ---------------- spectral norm of Wmlp (64x64), 20 power iters ----------------
__global__ void spectral(const float* __restrict__ W, float* __restrict__ sigma) {
    __shared__ float ub[64], vb[64];
    int t = threadIdx.x;
    ub[t] = 0.125f;
    __syncthreads();
    for (int it = 0; it < 20; it++) {
        float s = 0.f;
        for (int i = 0; i < 64; i++) s += W[i * 64 + t] * ub[i];
        float ss = s * s;
        for (int off = 1; off < 64; off <<= 1) ss += __shfl_xor(ss, off);
        float vn = s / (sqrtf(ss) + 1e-12f);
        __syncthreads();
        vb[t] = vn;
        __syncthreads();
        float s2 = 0.f;
        for (int j = 0; j < 64; j++) s2 += W[t * 64 + j] * vb[j];
        float ss2 = s2 * s2;
        for (int off = 1; off < 64; off <<= 1) ss2 += __shfl_xor(ss2, off);
        ub[t] = s2 / (sqrtf(ss2) + 1e-12f);
        __syncthreads();
    }
    float wvv = 0.f;
    for (int j = 0; j < 64; j++) wvv += W[t * 64 + j] * vb[j];
    float sg = ub[t] * wvv;
    for (int off = 1; off < 64; off <<= 1) sg += __shfl_xor(sg, off);
    if (t == 0) *sigma = sg;
}

// ---------------- finalize: head-mean + skip, tanh, @ (Wmlp/sigma) ----------------
__global__ __launch_bounds__(256) void finalize(const float* __restrict__ agg,
                                                const float* __restrict__ skip,
                                                const float* __restrict__ Wmlp,
                                                const float* __restrict__ sigma,
                                                float* __restrict__ out) {
    __shared__ float Ws[64 * 64];
    __shared__ float hid[4][64];
    int tid = threadIdx.x;
    for (int i = tid; i < 64 * 64; i += 256) Ws[i] = Wmlp[i];
    float inv_sigma = 1.0f / (*sigma);
    __syncthreads();
    int wave = tid >> 6, lane = tid & 63;
    int n = blockIdx.x * 4 + wave;
    if (n < NN) {
        const float* a = agg + (size_t)n * QKV;
        float mval = 0.25f * (a[lane] + a[64 + lane] + a[128 + lane] + a[192 + lane])
                     + skip[(size_t)n * 64 + lane];
        hid[wave][lane] = tanhf(mval);
    }
    __syncthreads();
    if (n < NN) {
        float acc = 0.f;
        for (int d = 0; d < 64; d++) acc += hid[wave][d] * Ws[d * 64 + lane];
        out[(size_t)n * 64 + lane] = acc * inv_sigma;
    }
}

extern "C" void kernel_launch(void* const* d_in, const int* in_sizes, int n_in,
                              void* d_out, int out_size, void* d_ws, size_t ws_size,
                              hipStream_t stream) {
    const float* x     = (const float*)d_in[0];
    const int*   ei    = (const int*)d_in[1];
    const float* Wq    = (const float*)d_in[2];
    const float* bq    = (const float*)d_in[3];
    const float* Wk    = (const float*)d_in[4];
    const float* bk    = (const float*)d_in[5];
    const float* Wv    = (const float*)d_in[6];
    const float* bv    = (const float*)d_in[7];
    const float* Wskip = (const float*)d_in[8];
    const float* bskip = (const float*)d_in[9];
    const float* Wmlp  = (const float*)d_in[10];
    float* out = (float*)d_out;

    // ---- workspace layout (all segments 16B-aligned) ----
    float* q    = (float*)d_ws;                  // NN*256
    float* agg  = q    + (size_t)NN * QKV;       // NN*256
    float* skip = agg  + (size_t)NN * QKV;       // NN*64
    float* bias = skip + (size_t)NN * OUTD;      // 832
    float* sig  = bias + NTOT;                   // 4 (padded)
    int* deg     = (int*)(sig + 4);              // NN
    int* incl    = deg + NN;                     // NN
    int* row_ptr = incl + NN;                    // NN+1 -> pad to NN+4
    int* cursor  = row_ptr + NN + 4;             // NN
    int* col_src = cursor + NN;                  // NE
    int* bsum    = col_src + NE;                 // 256
    unsigned short* kh = (unsigned short*)(bsum + 256);  // NN*256
    unsigned short* vh = kh + (size_t)NN * QKV;          // NN*256
    unsigned short* xh = vh + (size_t)NN * QKV;          // NN*128
    unsigned short* WT = xh + (size_t)NN * IND;          // 832*128

    // spectral sigma (tiny, independent)
    hipLaunchKernelGGL(spectral, dim3(1), dim3(64), 0, stream, Wmlp, sig);

    // CSR build
    hipLaunchKernelGGL(zero_int, dim3((NN + 255) / 256), dim3(256), 0, stream, deg, NN);
    hipLaunchKernelGGL(hist_dst, dim3((NE + 255) / 256), dim3(256), 0, stream, ei, deg);
    hipLaunchKernelGGL(scan1, dim3(SCAN_B), dim3(256), 0, stream, deg, incl, bsum);
    hipLaunchKernelGGL(scan2, dim3(1), dim3(256), 0, stream, bsum, row_ptr);
    hipLaunchKernelGGL(scan3, dim3(SCAN_B), dim3(256), 0, stream, deg, incl, bsum, row_ptr, cursor);
    hipLaunchKernelGGL(fill_csr, dim3((NE + 255) / 256), dim3(256), 0, stream, ei, cursor, col_src);

    // bf16 conversions
    hipLaunchKernelGGL(cvt_x, dim3(NN * IND / 4 / 256), dim3(256), 0, stream,
                       (const float4*)x, (ushort4*)xh);
    hipLaunchKernelGGL(pack_w, dim3((NTOT * 128 + 255) / 256), dim3(256), 0, stream,
                       Wq, bq, Wk, bk, Wv, bv, Wskip, bskip, WT, bias);

    // one fused MFMA GEMM for q|k|v|skip
    hipLaunchKernelGGL(gemm_mfma, dim3((NN + 63) / 64, NTOT / 64), dim3(256), 0, stream,
                       xh, WT, bias, q, kh, vh, skip);

    // fused per-node attention (CSR gather, online softmax)
    hipLaunchKernelGGL(fused_attn, dim3((NN + 3) / 4), dim3(256), 0, stream,
                       row_ptr, col_src, q, kh, vh, agg);

    // finalize
    hipLaunchKernelGGL(finalize, dim3((NN + 3) / 4), dim3(256), 0, stream,
                       agg, skip, Wmlp, sig, out);
}

// Round 7
// 318.375 us; speedup vs baseline: 4.7096x; 1.0817x over previous
//
#include <hip/hip_runtime.h>
#include <math.h>

#define NN 50000
#define NE 300000
#define IND 128
#define QKV 256      // HEADS*HID
#define QKVP 768     // packed q|k|v row stride (bf16)
#define OUTD 64
#define NTOT 832     // 256*3 + 64 packed output cols
#define NCT 13       // NTOT/64 col tiles
#define SCAN_B 196   // ceil(NN/256)

typedef __attribute__((ext_vector_type(8))) short bf16x8;
typedef __attribute__((ext_vector_type(4))) float f32x4;

__device__ inline unsigned short f2bf(float f) {
    unsigned u = __float_as_uint(f);
    u = (u + 0x7FFFu + ((u >> 16) & 1u)) >> 16;   // RNE
    return (unsigned short)u;
}
__device__ inline float b2f(unsigned short h) {
    return __uint_as_float(((unsigned)h) << 16);
}

// ---------------- pack W^T (bf16) + bias ----------------
__global__ __launch_bounds__(256) void pack_w(const float* __restrict__ Wq, const float* __restrict__ bq,
                                              const float* __restrict__ Wk, const float* __restrict__ bk,
                                              const float* __restrict__ Wv, const float* __restrict__ bv,
                                              const float* __restrict__ Wsk, const float* __restrict__ bsk,
                                              unsigned short* __restrict__ WT, float* __restrict__ bias) {
    int t = blockIdx.x * 256 + threadIdx.x;     // NTOT*128 threads
    if (t >= NTOT * 128) return;
    int col = t >> 7, kk = t & 127;
    const float* W; const float* B; int c; int ld;
    if (col < 256)      { W = Wq;  B = bq;  c = col;       ld = 256; }
    else if (col < 512) { W = Wk;  B = bk;  c = col - 256; ld = 256; }
    else if (col < 768) { W = Wv;  B = bv;  c = col - 512; ld = 256; }
    else                { W = Wsk; B = bsk; c = col - 768; ld = 64;  }
    WT[t] = f2bf(W[kk * ld + c]);               // WT[col][kk]
    if (kk == 0) bias[col] = B[c];
}

// ---------------- fused MFMA GEMM: [q|k|v] bf16 + skip fp32 ----------------
// grid = row blocks only; x staged once (fp32->bf16 in-flight); loop 13 col tiles.
__global__ __launch_bounds__(256) void gemm_mfma(const float* __restrict__ x,
                                                 const unsigned short* __restrict__ WT,
                                                 const float* __restrict__ bias,
                                                 unsigned short* __restrict__ qkvh,
                                                 float* __restrict__ skip) {
    __shared__ short As[64][136];   // 64 rows x 128 k (+8 pad)
    __shared__ short Bs[64][136];
    int tid = threadIdx.x;
    int wv = tid >> 6, lane = tid & 63;
    int row0 = blockIdx.x * 64;

    // stage A once: 64 rows x 128 fp32 -> bf16.  8 passes, float4 per thread.
#pragma unroll
    for (int p = 0; p < 8; p++) {
        int idx = p * 256 + tid;
        int r = idx >> 5, c4 = (idx & 31) * 4;
        int gr = row0 + r;
        float4 v = (gr < NN) ? *(const float4*)(x + (size_t)gr * IND + c4)
                             : make_float4(0.f, 0.f, 0.f, 0.f);
        ushort4 o;
        o.x = f2bf(v.x); o.y = f2bf(v.y); o.z = f2bf(v.z); o.w = f2bf(v.w);
        *(ushort4*)(&As[r][c4]) = o;
    }

    int lr = lane & 15;
    int koff = (lane >> 4) * 8;
    int arow = wv * 16 + lr;
    int rbase = wv * 16 + ((lane >> 4) << 2);

    for (int ct = 0; ct < NCT; ct++) {
        int col0 = ct * 64;
        __syncthreads();                        // As ready (it=0) / Bs reads done (it>0)
#pragma unroll
        for (int rr = 0; rr < 4; rr++) {        // stage B tile (16B per thread)
            int idx = rr * 256 + tid;
            int r = idx >> 4, c8 = (idx & 15) * 8;
            *(int4*)(&Bs[r][c8]) = *(const int4*)(WT + (size_t)(col0 + r) * 128 + c8);
        }
        __syncthreads();

        f32x4 acc[4] = {};
#pragma unroll
        for (int k0 = 0; k0 < 128; k0 += 32) {
            bf16x8 a = *(bf16x8*)(&As[arow][k0 + koff]);
#pragma unroll
            for (int cf = 0; cf < 4; cf++) {
                bf16x8 b = *(bf16x8*)(&Bs[cf * 16 + lr][k0 + koff]);
                acc[cf] = __builtin_amdgcn_mfma_f32_16x16x32_bf16(a, b, acc[cf], 0, 0, 0);
            }
        }

        if (col0 < QKVP) {                      // q|k|v bf16, packed row stride 768
#pragma unroll
            for (int cf = 0; cf < 4; cf++) {
                int c = col0 + cf * 16 + lr; float bb = bias[c];
#pragma unroll
                for (int r = 0; r < 4; r++) {
                    int gr = row0 + rbase + r;
                    if (gr < NN) qkvh[(size_t)gr * QKVP + c] = f2bf(acc[cf][r] + bb);
                }
            }
        } else {                                // skip fp32
#pragma unroll
            for (int cf = 0; cf < 4; cf++) {
                int c = col0 + cf * 16 + lr; float bb = bias[c];
#pragma unroll
                for (int r = 0; r < 4; r++) {
                    int gr = row0 + rbase + r;
                    if (gr < NN) skip[(size_t)gr * OUTD + (c - QKVP)] = acc[cf][r] + bb;
                }
            }
        }
    }
}

// ---------------- CSR build ----------------
__global__ void hist_dst(const int* __restrict__ ei, int* __restrict__ deg) {
    int t = blockIdx.x * blockDim.x + threadIdx.x;
    if (t < NE) atomicAdd(&deg[ei[NE + t]], 1);
}
__global__ __launch_bounds__(256) void scan1(const int* __restrict__ deg,
                                             int* __restrict__ incl, int* __restrict__ bsum) {
    __shared__ int s[256];
    int tid = threadIdx.x, i = blockIdx.x * 256 + tid;
    int v = (i < NN) ? deg[i] : 0;
    s[tid] = v; __syncthreads();
    for (int off = 1; off < 256; off <<= 1) {
        int t2 = (tid >= off) ? s[tid - off] : 0;
        __syncthreads(); s[tid] += t2; __syncthreads();
    }
    if (i < NN) incl[i] = s[tid];
    if (tid == 255) bsum[blockIdx.x] = s[255];
}
__global__ __launch_bounds__(256) void scan2(int* __restrict__ bsum, int* __restrict__ row_ptr) {
    __shared__ int s[256];
    int tid = threadIdx.x;
    int v = (tid < SCAN_B) ? bsum[tid] : 0;
    s[tid] = v; __syncthreads();
    for (int off = 1; off < 256; off <<= 1) {
        int t2 = (tid >= off) ? s[tid - off] : 0;
        __syncthreads(); s[tid] += t2; __syncthreads();
    }
    if (tid < SCAN_B) bsum[tid] = s[tid] - v;   // exclusive block offsets
    if (tid == 255) row_ptr[NN] = s[255];       // total = NE
}
__global__ __launch_bounds__(256) void scan3(const int* __restrict__ deg, const int* __restrict__ incl,
                                             const int* __restrict__ bsum,
                                             int* __restrict__ row_ptr, int* __restrict__ cursor) {
    int i = blockIdx.x * 256 + threadIdx.x;
    if (i < NN) {
        int e = incl[i] - deg[i] + bsum[blockIdx.x];
        row_ptr[i] = e; cursor[i] = e;
    }
}
__global__ void fill_csr(const int* __restrict__ ei, int* __restrict__ cursor,
                         int* __restrict__ col_src) {
    int t = blockIdx.x * blockDim.x + threadIdx.x;
    if (t < NE) {
        int pos = atomicAdd(&cursor[ei[NE + t]], 1);
        col_src[pos] = ei[t];
    }
}

// ---------------- fused attention: one wave per dst node, online softmax ----------------
__global__ __launch_bounds__(256) void fused_attn(const int* __restrict__ row_ptr,
                                                  const int* __restrict__ col_src,
                                                  const unsigned short* __restrict__ qkvh,
                                                  float* __restrict__ agg) {
    int wv = threadIdx.x >> 6;
    int lane = threadIdx.x & 63;
    int n = blockIdx.x * 4 + wv;
    if (n >= NN) return;

    ushort4 qq = *(const ushort4*)(qkvh + (size_t)n * QKVP + lane * 4);
    float4 qv = make_float4(b2f(qq.x), b2f(qq.y), b2f(qq.z), b2f(qq.w));
    float m = -1e30f, d = 0.f;
    float4 o = make_float4(0.f, 0.f, 0.f, 0.f);

    int jb = row_ptr[n], je = row_ptr[n + 1];
    for (int j = jb; j < je; j++) {
        int src = col_src[j];
        const unsigned short* srow = qkvh + (size_t)src * QKVP;
        ushort4 kq = *(const ushort4*)(srow + 256 + lane * 4);
        float s = qv.x * b2f(kq.x) + qv.y * b2f(kq.y) + qv.z * b2f(kq.z) + qv.w * b2f(kq.w);
        s += __shfl_xor(s, 1);
        s += __shfl_xor(s, 2);
        s += __shfl_xor(s, 4);
        s += __shfl_xor(s, 8);
        s *= 0.125f;                            // / sqrt(64)
        float mn = fmaxf(m, s);
        float scale = __expf(m - mn);
        float e = __expf(s - mn);
        d = d * scale + e;
        ushort4 vq = *(const ushort4*)(srow + 512 + lane * 4);
        o.x = o.x * scale + e * b2f(vq.x);
        o.y = o.y * scale + e * b2f(vq.y);
        o.z = o.z * scale + e * b2f(vq.z);
        o.w = o.w * scale + e * b2f(vq.w);
        m = mn;
    }
    float inv = 1.0f / (d + 1e-16f);
    *(float4*)(agg + (size_t)n * QKV + lane * 4) =
        make_float4(o.x * inv, o.y * inv, o.z * inv, o.w * inv);
}

// ---------------- spectral norm of Wmlp (64x64), 20 power iters ----------------
__global__ void spectral(const float* __restrict__ W, float* __restrict__ sigma) {
    __shared__ float ub[64], vb[64];
    int t = threadIdx.x;
    ub[t] = 0.125f;
    __syncthreads();
    for (int it = 0; it < 20; it++) {
        float s = 0.f;
        for (int i = 0; i < 64; i++) s += W[i * 64 + t] * ub[i];
        float ss = s * s;
        for (int off = 1; off < 64; off <<= 1) ss += __shfl_xor(ss, off);
        float vn = s / (sqrtf(ss) + 1e-12f);
        __syncthreads();
        vb[t] = vn;
        __syncthreads();
        float s2 = 0.f;
        for (int j = 0; j < 64; j++) s2 += W[t * 64 + j] * vb[j];
        float ss2 = s2 * s2;
        for (int off = 1; off < 64; off <<= 1) ss2 += __shfl_xor(ss2, off);
        ub[t] = s2 / (sqrtf(ss2) + 1e-12f);
        __syncthreads();
    }
    float wvv = 0.f;
    for (int j = 0; j < 64; j++) wvv += W[t * 64 + j] * vb[j];
    float sg = ub[t] * wvv;
    for (int off = 1; off < 64; off <<= 1) sg += __shfl_xor(sg, off);
    if (t == 0) *sigma = sg;
}

// ---------------- finalize: head-mean + skip, tanh, @ (Wmlp/sigma) ----------------
__global__ __launch_bounds__(256) void finalize(const float* __restrict__ agg,
                                                const float* __restrict__ skip,
                                                const float* __restrict__ Wmlp,
                                                const float* __restrict__ sigma,
                                                float* __restrict__ out) {
    __shared__ float Ws[64 * 64];
    __shared__ float hid[4][64];
    int tid = threadIdx.x;
    for (int i = tid; i < 64 * 64; i += 256) Ws[i] = Wmlp[i];
    float inv_sigma = 1.0f / (*sigma);
    __syncthreads();
    int wave = tid >> 6, lane = tid & 63;
    int n = blockIdx.x * 4 + wave;
    if (n < NN) {
        const float* a = agg + (size_t)n * QKV;
        float mval = 0.25f * (a[lane] + a[64 + lane] + a[128 + lane] + a[192 + lane])
                     + skip[(size_t)n * 64 + lane];
        hid[wave][lane] = tanhf(mval);
    }
    __syncthreads();
    if (n < NN) {
        float acc = 0.f;
        for (int d = 0; d < 64; d++) acc += hid[wave][d] * Ws[d * 64 + lane];
        out[(size_t)n * 64 + lane] = acc * inv_sigma;
    }
}

extern "C" void kernel_launch(void* const* d_in, const int* in_sizes, int n_in,
                              void* d_out, int out_size, void* d_ws, size_t ws_size,
                              hipStream_t stream) {
    const float* x     = (const float*)d_in[0];
    const int*   ei    = (const int*)d_in[1];
    const float* Wq    = (const float*)d_in[2];
    const float* bq    = (const float*)d_in[3];
    const float* Wk    = (const float*)d_in[4];
    const float* bk    = (const float*)d_in[5];
    const float* Wv    = (const float*)d_in[6];
    const float* bv    = (const float*)d_in[7];
    const float* Wskip = (const float*)d_in[8];
    const float* bskip = (const float*)d_in[9];
    const float* Wmlp  = (const float*)d_in[10];
    float* out = (float*)d_out;

    // ---- workspace layout (16B-aligned segments) ----
    float* agg  = (float*)d_ws;                  // NN*256
    float* skip = agg  + (size_t)NN * QKV;       // NN*64
    float* bias = skip + (size_t)NN * OUTD;      // 832
    float* sig  = bias + NTOT;                   // 4 (padded)
    int* deg     = (int*)(sig + 4);              // NN
    int* incl    = deg + NN;                     // NN
    int* row_ptr = incl + NN;                    // NN+1 -> pad to NN+4
    int* cursor  = row_ptr + NN + 4;             // NN
    int* col_src = cursor + NN;                  // NE
    int* bsum    = col_src + NE;                 // 256
    unsigned short* qkvh = (unsigned short*)(bsum + 256);  // NN*768
    unsigned short* WT   = qkvh + (size_t)NN * QKVP;       // 832*128

    // spectral sigma (tiny, independent)
    hipLaunchKernelGGL(spectral, dim3(1), dim3(64), 0, stream, Wmlp, sig);

    // CSR build
    hipMemsetAsync(deg, 0, NN * sizeof(int), stream);
    hipLaunchKernelGGL(hist_dst, dim3((NE + 255) / 256), dim3(256), 0, stream, ei, deg);
    hipLaunchKernelGGL(scan1, dim3(SCAN_B), dim3(256), 0, stream, deg, incl, bsum);
    hipLaunchKernelGGL(scan2, dim3(1), dim3(256), 0, stream, bsum, row_ptr);
    hipLaunchKernelGGL(scan3, dim3(SCAN_B), dim3(256), 0, stream, deg, incl, bsum, row_ptr, cursor);
    hipLaunchKernelGGL(fill_csr, dim3((NE + 255) / 256), dim3(256), 0, stream, ei, cursor, col_src);

    // weight pack (bf16)
    hipLaunchKernelGGL(pack_w, dim3((NTOT * 128 + 255) / 256), dim3(256), 0, stream,
                       Wq, bq, Wk, bk, Wv, bv, Wskip, bskip, WT, bias);

    // fused MFMA GEMM: stages x once per row block, loops col tiles
    hipLaunchKernelGGL(gemm_mfma, dim3((NN + 63) / 64), dim3(256), 0, stream,
                       x, WT, bias, qkvh, skip);

    // fused per-node attention (CSR gather, online softmax)
    hipLaunchKernelGGL(fused_attn, dim3((NN + 3) / 4), dim3(256), 0, stream,
                       row_ptr, col_src, qkvh, agg);

    // finalize
    hipLaunchKernelGGL(finalize, dim3((NN + 3) / 4), dim3(256), 0, stream,
                       agg, skip, Wmlp, sig, out);
}